// Round 1
// baseline (275.377 us; speedup 1.0000x reference)
//
#include <hip/hip_runtime.h>

typedef short short8 __attribute__((ext_vector_type(8)));
typedef float f32x4 __attribute__((ext_vector_type(4)));
typedef unsigned short ushort4_t __attribute__((ext_vector_type(4)));

#define O_CH 128
#define I_CH 128
#define HW 112
#define CHP 72     // LDS channel stride: 64 ch + 8 pad (16B-aligned rows, bank-spread)
#define NCOL 114   // 112 cols + 2 halo

__device__ __forceinline__ unsigned short f2bf(float f) {
  union { float f; unsigned u; } v; v.f = f;
  unsigned r = v.u + 0x7FFFu + ((v.u >> 16) & 1u);   // RNE
  return (unsigned short)(r >> 16);
}

__global__ void wsynth_kernel(const float* __restrict__ core,
                              const float* __restrict__ periph,
                              const float* __restrict__ thr,
                              const float* __restrict__ scale,
                              unsigned short* __restrict__ Wb) {
  int idx = blockIdx.x * blockDim.x + threadIdx.x;   // o*128 + i
  if (idx >= O_CH * I_CH) return;
  int o = idx >> 7;
  float c = core[idx];
  float s = scale[0];
  float g = 1.0f / (1.0f + __expf(-s * (fabsf(c) - thr[o])));
#pragma unroll
  for (int tap = 0; tap < 9; ++tap) {
    float p  = (tap == 4) ? 1.0f : periph[tap < 4 ? tap : tap - 1];
    float gg = (tap == 4) ? 1.0f : g;
    Wb[tap * (O_CH * I_CH) + idx] = f2bf(c * p * gg);   // layout [tap][o][i]
  }
}

__global__ __launch_bounds__(256, 2)
void conv_kernel(const float* __restrict__ X,
                 const unsigned short* __restrict__ Wb,
                 float* __restrict__ Out) {
  __shared__ unsigned short Xs[3 * NCOL * CHP];   // 49,248 B

  const int bid = blockIdx.x;
  const int b = bid / HW;
  const int y = bid - b * HW;

  const int t   = threadIdx.x;
  const int wv  = t >> 6;        // wave 0..3 -> o block
  const int l   = t & 63;
  const int ln  = l & 15;        // frag row/col lane
  const int lk4 = l >> 4;        // k-group 0..3

  // staging coords: thread -> (col, channel-half)
  const int c    = t & 127;
  const int i2   = t >> 7;       // 0..1
  const int c_lds = (c < 112) ? (c + 1) : ((c == 112) ? 0 : 113);
  const bool wr_ok = (c <= 113);

  f32x4 acc[2][7];
#pragma unroll
  for (int mr = 0; mr < 2; ++mr)
#pragma unroll
    for (int nf = 0; nf < 7; ++nf)
      acc[mr][nf] = (f32x4)0.0f;

  const unsigned short* wbase = Wb + (wv * 32 + ln) * I_CH + lk4 * 8;
  const unsigned short* bbase = &Xs[ln * CHP + lk4 * 8];

  for (int h = 0; h < 2; ++h) {
    if (h) __syncthreads();   // previous half's compute done before overwrite
    // ---- stage channels [h*64, h*64+64) of rows y-1..y+1 as bf16 ----
#pragma unroll
    for (int r = 0; r < 3; ++r) {
      const int row = y + r - 1;
      const bool ld = (row >= 0) && (row < 112) && (c < 112);
      const float* src = X + (((b * I_CH + h * 64) * HW + row) * HW + c);
#pragma unroll
      for (int q = 0; q < 8; ++q) {
        const int ig = (i2 * 8 + q) * 4;     // local channel 0,4,...,60
        float v0 = 0.f, v1 = 0.f, v2 = 0.f, v3 = 0.f;
        if (ld) {
          v0 = src[(ig + 0) * (HW * HW)];
          v1 = src[(ig + 1) * (HW * HW)];
          v2 = src[(ig + 2) * (HW * HW)];
          v3 = src[(ig + 3) * (HW * HW)];
        }
        if (wr_ok) {
          ushort4_t pk;
          pk.x = f2bf(v0); pk.y = f2bf(v1); pk.z = f2bf(v2); pk.w = f2bf(v3);
          *reinterpret_cast<ushort4_t*>(&Xs[(r * NCOL + c_lds) * CHP + ig]) = pk;
        }
      }
    }
    __syncthreads();

    // ---- 9 taps x 2 channel-chunks of K=32 ----
#pragma unroll
    for (int tap = 0; tap < 9; ++tap) {
      const int r   = tap / 3;   // dy+1
      const int dxp = tap % 3;   // dx+1
#pragma unroll
      for (int ci = 0; ci < 2; ++ci) {
        const unsigned short* wp = wbase + tap * (O_CH * I_CH) + h * 64 + ci * 32;
        short8 a0 = *reinterpret_cast<const short8*>(wp);
        short8 a1 = *reinterpret_cast<const short8*>(wp + 16 * I_CH);
#pragma unroll
        for (int nf = 0; nf < 7; ++nf) {
          const unsigned short* bp = bbase + (r * NCOL + dxp + nf * 16) * CHP + ci * 32;
          short8 bb = *reinterpret_cast<const short8*>(bp);
          acc[0][nf] = __builtin_amdgcn_mfma_f32_16x16x32_bf16(a0, bb, acc[0][nf], 0, 0, 0);
          acc[1][nf] = __builtin_amdgcn_mfma_f32_16x16x32_bf16(a1, bb, acc[1][nf], 0, 0, 0);
        }
      }
    }
  }

  // ---- epilogue: C/D map col=lane&15, row=(lane>>4)*4+j ----
  const int obase = wv * 32 + lk4 * 4;
  float* outp = Out + ((size_t)b * O_CH * HW * HW) + (size_t)y * HW;
#pragma unroll
  for (int mr = 0; mr < 2; ++mr) {
#pragma unroll
    for (int j = 0; j < 4; ++j) {
      const int o = obase + mr * 16 + j;
      float* po = outp + (size_t)o * (HW * HW);
#pragma unroll
      for (int nf = 0; nf < 7; ++nf) {
        po[nf * 16 + ln] = acc[mr][nf][j];
      }
    }
  }
}

extern "C" void kernel_launch(void* const* d_in, const int* in_sizes, int n_in,
                              void* d_out, int out_size, void* d_ws, size_t ws_size,
                              hipStream_t stream) {
  const float* x      = (const float*)d_in[0];
  const float* core   = (const float*)d_in[1];
  const float* periph = (const float*)d_in[2];
  const float* thr    = (const float*)d_in[3];
  const float* scale  = (const float*)d_in[4];
  unsigned short* Wb  = (unsigned short*)d_ws;   // 9*128*128*2 = 294,912 B

  wsynth_kernel<<<(O_CH * I_CH + 255) / 256, 256, 0, stream>>>(core, periph, thr, scale, Wb);

  const int grid = 32 * HW;   // one WG per (batch, output row)
  conv_kernel<<<grid, 256, 0, stream>>>(x, Wb, (float*)d_out);
}